// Round 9
// baseline (222.586 us; speedup 1.0000x reference)
//
#include <hip/hip_runtime.h>
#include <hip/hip_bf16.h>
#include <math.h>

#define LC 18432              // 144*128
#define LOG2E 1.4426950408889634f

typedef short bf16x8 __attribute__((ext_vector_type(8)));
typedef float f32x4 __attribute__((ext_vector_type(4)));

#define MFMA16 __builtin_amdgcn_mfma_f32_16x16x32_bf16
#define WAITVM0 asm volatile("s_waitcnt vmcnt(0)" ::: "memory")

__device__ __forceinline__ float fast_exp2(float x) {
#if __has_builtin(__builtin_amdgcn_exp2f)
  return __builtin_amdgcn_exp2f(x);
#else
  return exp2f(x);
#endif
}
__device__ __forceinline__ float fast_log2(float x) {
#if __has_builtin(__builtin_amdgcn_logf)
  return __builtin_amdgcn_logf(x);
#else
  return log2f(x);
#endif
}

__device__ __forceinline__ ushort f2bf(float x) {
  __hip_bfloat16 h = __float2bfloat16(x);
  return __builtin_bit_cast(ushort, h);
}

// byte offset in a 256-byte-row swizzled tile (128 bf16 cols)
__device__ __forceinline__ int swb(int row, int x) {
  return (row << 8) + (x ^ ((row & 15) << 4));
}
// byte offset in a 512-byte-row swizzled tile (256 bf16 cols)
__device__ __forceinline__ int swb9(int row, int x) {
  return (row << 9) + (x ^ ((row & 15) << 4));
}

typedef const __attribute__((address_space(1))) unsigned int g_u32;
typedef __attribute__((address_space(3))) unsigned int l_u32;
__device__ __forceinline__ void gl_lds16(const ushort* g, ushort* l) {
  __builtin_amdgcn_global_load_lds((g_u32*)g, (l_u32*)l, 16, 0, 0);
}

// ---------------- prep: preds1 (bid<32) + posimg convert (bid>=32) ----------
__global__ __launch_bounds__(256) void prep_all(
    const float* __restrict__ f_t, const float* __restrict__ fmap_tp1,
    const float* __restrict__ W1, const float* __restrict__ b1,
    ushort* __restrict__ p1img, ushort* __restrict__ posimg,
    float* __restrict__ out) {
  const int bid = blockIdx.x, t = threadIdx.x;
  if (bid == 0 && t == 0) *out = 0.f;  // replaces memset dispatch
  const int wave = t >> 6, lane = t & 63, lo = lane & 15, hi = lane >> 4;

  if (bid < 32) {
    // ---- preds1: rows rc*32..+32, d-cols dh*64..+64, K=256 ----
    __shared__ __align__(16) ushort sF[32 * 256];  // 16 KB
    __shared__ __align__(16) ushort sW[64 * 256];  // 32 KB
    const int rc = bid >> 1, dh = bid & 1;
#pragma unroll
    for (int k = 0; k < 8; ++k) {
      int idx = t + k * 256;
      int row = idx >> 6, c4 = (idx & 63) << 2;
      float4 v = *(const float4*)(f_t + (size_t)(rc * 32 + row) * 256 + c4);
      ushort4 h = {f2bf(v.x), f2bf(v.y), f2bf(v.z), f2bf(v.w)};
      *(ushort4*)((char*)sF + swb9(row, c4 << 1)) = h;
    }
#pragma unroll
    for (int k = 0; k < 16; ++k) {
      int idx = t + k * 256;
      int row = idx >> 6, c4 = (idx & 63) << 2;
      float4 v = *(const float4*)(W1 + (size_t)(dh * 64 + row) * 256 + c4);
      ushort4 h = {f2bf(v.x), f2bf(v.y), f2bf(v.z), f2bf(v.w)};
      *(ushort4*)((char*)sW + swb9(row, c4 << 1)) = h;
    }
    __syncthreads();
    const int rn = (wave & 1) * 16, wd = (wave >> 1) * 32;
    f32x4 acc[2] = {};
#pragma unroll
    for (int s = 0; s < 8; ++s) {
      int x = s * 64 + hi * 16;
      bf16x8 a = *(const bf16x8*)((const char*)sF + swb9(rn + lo, x));
#pragma unroll
      for (int j = 0; j < 2; ++j) {
        bf16x8 b = *(const bf16x8*)((const char*)sW + swb9(wd + j * 16 + lo, x));
        acc[j] = MFMA16(a, b, acc[j], 0, 0, 0);
      }
    }
#pragma unroll
    for (int j = 0; j < 2; ++j) {
      int d = dh * 64 + wd + j * 16 + lo;
      float bb = b1[d];
#pragma unroll
      for (int e = 0; e < 4; ++e) {
        int R = rc * 32 + rn + hi * 4 + e;
        int tile = R >> 6, rin = R & 63;
        *(ushort*)((char*)p1img + (size_t)tile * 16384 + (rin << 8) +
                   ((2 * d) ^ ((rin & 15) << 4))) =
            f2bf((acc[j][e] + bb) * LOG2E);
      }
    }
  } else {
    // ---- posimg tile (l, mtt): fp32 -> swizzled bf16 ----
    const int bb = bid - 32;
    const int l = bb >> 3, mtt = bb & 7;
    ushort* tile = posimg + (size_t)bb * 8192;
#pragma unroll
    for (int k = 0; k < 8; ++k) {
      int idx = t + k * 256;
      int row = idx >> 5, c4 = (idx & 31) << 2;
      float4 v = *(const float4*)(fmap_tp1 + (size_t)(mtt * 64 + row) * LC + l * 128 + c4);
      ushort4 h = {f2bf(v.x), f2bf(v.y), f2bf(v.z), f2bf(v.w)};
      *(ushort4*)((char*)tile + swb(row, c4 << 1)) = h;
    }
  }
}

// ---------------- fused main ----------------
// Phase A overlays {loc, W2-halves, preds2} into the pos double-buffer.
// Loop = round-4 structure: gl_lds bf16 posimg, 1 barrier/iter.
__global__ __launch_bounds__(512, 6) void stdim_fused(
    const ushort* __restrict__ p1img, const float* __restrict__ fmap_t,
    const ushort* __restrict__ posimg, const float* __restrict__ W2,
    const float* __restrict__ b2, float* __restrict__ out) {
  __shared__ __align__(16) ushort sB[2][8192];  // 32 KB total
  __shared__ float s_rows[2][64][2];
  __shared__ float s_diag[2][64];
  __shared__ float s_red[8];

  const int bid = blockIdx.x;
  const int work = (bid & 7) * 144 + (bid >> 3);  // XCD-chunked (1152 % 8 == 0)
  const int l = work >> 3, rb = work & 7;
  const int t = threadIdx.x;
  const int wave = t >> 6, lane = t & 63, lo = lane & 15, hi = lane >> 4;
  const int ty_ = wave >> 2, wr = (wave >> 1) & 1, wc = wave & 1;

  // ---- phase A: loc -> sB0, W2 half0 -> sB1 ----
#pragma unroll
  for (int k = 0; k < 4; ++k) {
    int idx = t + k * 512;
    int row = idx >> 5, c4 = (idx & 31) << 2;
    float4 v = *(const float4*)(fmap_t + (size_t)(rb * 64 + row) * LC + l * 128 + c4);
    ushort4 h = {f2bf(v.x), f2bf(v.y), f2bf(v.z), f2bf(v.w)};
    *(ushort4*)((char*)sB[0] + swb(row, c4 << 1)) = h;
  }
#pragma unroll
  for (int k = 0; k < 4; ++k) {
    int idx = t + k * 512;
    int row = idx >> 5, c4 = (idx & 31) << 2;
    float4 v = *(const float4*)(W2 + (size_t)row * 128 + c4);
    ushort4 h = {f2bf(v.x), f2bf(v.y), f2bf(v.z), f2bf(v.w)};
    *(ushort4*)((char*)sB[1] + swb(row, c4 << 1)) = h;
  }
  const int wn = (wave & 1) * 32, wd = (wave >> 1) * 32;  // wd in {0,32,64,96}
  const float b2a = b2[wd + lo], b2b = b2[wd + 16 + lo];
  __syncthreads();

  // ---- preds2 = loc @ W2^T, W2 in two 64-row halves ----
  f32x4 acc2[2][2] = {};
  const int wdl = wd & 63;
  if (wave < 4) {  // wd in {0,32}: half 0
#pragma unroll
    for (int s = 0; s < 4; ++s) {
      int x = s * 64 + hi * 16;
      bf16x8 a0 = *(const bf16x8*)((const char*)sB[0] + swb(wn + lo, x));
      bf16x8 a1 = *(const bf16x8*)((const char*)sB[0] + swb(wn + 16 + lo, x));
#pragma unroll
      for (int j = 0; j < 2; ++j) {
        bf16x8 b = *(const bf16x8*)((const char*)sB[1] + swb(wdl + j * 16 + lo, x));
        acc2[0][j] = MFMA16(a0, b, acc2[0][j], 0, 0, 0);
        acc2[1][j] = MFMA16(a1, b, acc2[1][j], 0, 0, 0);
      }
    }
  }
  __syncthreads();
#pragma unroll
  for (int k = 0; k < 4; ++k) {  // W2 half1 -> sB1
    int idx = t + k * 512;
    int row = idx >> 5, c4 = (idx & 31) << 2;
    float4 v = *(const float4*)(W2 + (size_t)(64 + row) * 128 + c4);
    ushort4 h = {f2bf(v.x), f2bf(v.y), f2bf(v.z), f2bf(v.w)};
    *(ushort4*)((char*)sB[1] + swb(row, c4 << 1)) = h;
  }
  __syncthreads();
  if (wave >= 4) {  // wd in {64,96}: half 1
#pragma unroll
    for (int s = 0; s < 4; ++s) {
      int x = s * 64 + hi * 16;
      bf16x8 a0 = *(const bf16x8*)((const char*)sB[0] + swb(wn + lo, x));
      bf16x8 a1 = *(const bf16x8*)((const char*)sB[0] + swb(wn + 16 + lo, x));
#pragma unroll
      for (int j = 0; j < 2; ++j) {
        bf16x8 b = *(const bf16x8*)((const char*)sB[1] + swb(wdl + j * 16 + lo, x));
        acc2[0][j] = MFMA16(a0, b, acc2[0][j], 0, 0, 0);
        acc2[1][j] = MFMA16(a1, b, acc2[1][j], 0, 0, 0);
      }
    }
  }
  __syncthreads();  // all loc reads done -> sB0 reusable

  // ---- write preds2*log2e -> sB0 ----
#pragma unroll
  for (int i2 = 0; i2 < 2; ++i2)
#pragma unroll
    for (int j = 0; j < 2; ++j)
#pragma unroll
      for (int e = 0; e < 4; ++e) {
        int r = wn + i2 * 16 + hi * 4 + e;
        int d = wd + j * 16 + lo;
        *(ushort*)((char*)sB[0] + (r << 8) + ((2 * d) ^ ((r & 15) << 4))) =
            f2bf((acc2[i2][j][e] + (j ? b2b : b2a)) * LOG2E);
      }
  __syncthreads();  // preds2 visible

  // ---- A fragments to regs (loss1 from p1img global; loss2 from sB0) ----
  bf16x8 af[2][4];
  if (ty_ == 0) {
    const char* aimg = (const char*)(p1img + (size_t)rb * 8192);
#pragma unroll
    for (int rt = 0; rt < 2; ++rt)
#pragma unroll
      for (int s = 0; s < 4; ++s)
        af[rt][s] = *(const bf16x8*)(aimg + swb(wr * 32 + rt * 16 + lo, s * 64 + hi * 16));
  } else {
#pragma unroll
    for (int rt = 0; rt < 2; ++rt)
#pragma unroll
      for (int s = 0; s < 4; ++s)
        af[rt][s] = *(const bf16x8*)((const char*)sB[0] +
                                     swb(wr * 32 + rt * 16 + lo, s * 64 + hi * 16));
  }
  __syncthreads();  // af ds_reads drained -> sB0 reusable for pos tiles

  // ---- stage pos tile 0 via global_load_lds (linear dest == swizzled img) ----
  const ushort* ptile = posimg + (size_t)(l * 8) * 8192;
  const ushort* gsrc = ptile + wave * 1024 + lane * 8;
  {
    ushort* dst = (ushort*)sB[0] + wave * 1024;
    gl_lds16(gsrc, dst);
    gl_lds16(gsrc + 512, dst + 512);
  }
  WAITVM0;
  __syncthreads();

  float sm0[4] = {0.f, 0.f, 0.f, 0.f}, sm1[4] = {0.f, 0.f, 0.f, 0.f};

  // ---- main loop (round-4 structure): prefetch mt+1, 1 barrier/iter ----
#pragma unroll
  for (int mt = 0; mt < 8; ++mt) {
    const int cur = mt & 1;
    if (mt < 7) {
      const ushort* src = gsrc + (size_t)(mt + 1) * 8192;
      ushort* dst = (ushort*)sB[cur ^ 1] + wave * 1024;
      gl_lds16(src, dst);
      gl_lds16(src + 512, dst + 512);
    }
    f32x4 a00 = {}, a01 = {}, a10 = {}, a11 = {};
    __builtin_amdgcn_s_setprio(1);
#pragma unroll
    for (int s = 0; s < 4; ++s) {
      int x = s * 64 + hi * 16;
      bf16x8 b0 = *(const bf16x8*)((const char*)sB[cur] + swb(wc * 32 + lo, x));
      bf16x8 b1 = *(const bf16x8*)((const char*)sB[cur] + swb(wc * 32 + 16 + lo, x));
      a00 = MFMA16(af[0][s], b0, a00, 0, 0, 0);
      a01 = MFMA16(af[0][s], b1, a01, 0, 0, 0);
      a10 = MFMA16(af[1][s], b0, a10, 0, 0, 0);
      a11 = MFMA16(af[1][s], b1, a11, 0, 0, 0);
    }
    __builtin_amdgcn_s_setprio(0);
#pragma unroll
    for (int i = 0; i < 4; ++i) {
      sm0[i] += fast_exp2(a00[i]) + fast_exp2(a01[i]);
      sm1[i] += fast_exp2(a10[i]) + fast_exp2(a11[i]);
    }
    if (mt == rb && wc == wr) {
#pragma unroll
      for (int i = 0; i < 4; ++i) {
        if (lo == hi * 4 + i) {
          s_diag[ty_][wr * 32 + hi * 4 + i] = a00[i];
          s_diag[ty_][wr * 32 + 16 + hi * 4 + i] = a11[i];
        }
      }
    }
    __syncthreads();  // drains vmcnt -> tile mt+1 ready; WAR fence for next prefetch
  }

  // ---- reduce the 16 lo-lanes of each row-group ----
#pragma unroll
  for (int i = 0; i < 4; ++i) {
    float v0 = sm0[i], v1 = sm1[i];
#pragma unroll
    for (int st = 1; st <= 8; st <<= 1) {
      v0 += __shfl_xor(v0, st);
      v1 += __shfl_xor(v1, st);
    }
    sm0[i] = v0;
    sm1[i] = v1;
  }
  if (lo == 0) {
#pragma unroll
    for (int i = 0; i < 4; ++i) {
      s_rows[ty_][wr * 32 + hi * 4 + i][wc] = sm0[i];
      s_rows[ty_][wr * 32 + 16 + hi * 4 + i][wc] = sm1[i];
    }
  }
  __syncthreads();

  float part = 0.f;
  if (t < 128) {
    int ty = t >> 6, r = t & 63;
    float tot = s_rows[ty][r][0] + s_rows[ty][r][1];
    part = fast_log2(tot) - s_diag[ty][r];
  }
#pragma unroll
  for (int st = 1; st <= 32; st <<= 1) part += __shfl_xor(part, st);
  if (lane == 0) s_red[wave] = part;
  __syncthreads();
  if (t == 0) {
    float s = 0.f;
#pragma unroll
    for (int w = 0; w < 8; ++w) s += s_red[w];
    atomicAdd(out, s * (0.6931471805599453f / 73728.0f));
  }
}

extern "C" void kernel_launch(void* const* d_in, const int* in_sizes, int n_in,
                              void* d_out, int out_size, void* d_ws, size_t ws_size,
                              hipStream_t stream) {
  const float* f_t      = (const float*)d_in[0];
  const float* fmap_t   = (const float*)d_in[1];
  const float* fmap_tp1 = (const float*)d_in[2];
  const float* W1       = (const float*)d_in[3];
  const float* b1       = (const float*)d_in[4];
  const float* W2       = (const float*)d_in[5];
  const float* b2       = (const float*)d_in[6];
  float* out = (float*)d_out;

  // ws: p1img 8x8192 ushorts (128 KB) | posimg 1152x8192 ushorts (18.9 MB)
  ushort* p1img  = (ushort*)d_ws;
  ushort* posimg = p1img + 8 * 8192;

  prep_all<<<32 + 1152, 256, 0, stream>>>(f_t, fmap_tp1, W1, b1, p1img, posimg, out);
  stdim_fused<<<1152, 512, 0, stream>>>(p1img, fmap_t, posimg, W2, b2, out);
}

// Round 10
// 175.382 us; speedup vs baseline: 1.2691x; 1.2691x over previous
//
#include <hip/hip_runtime.h>
#include <hip/hip_bf16.h>
#include <math.h>

#define LC 18432              // 144*128
#define LOG2E 1.4426950408889634f

typedef short bf16x8 __attribute__((ext_vector_type(8)));
typedef float f32x4 __attribute__((ext_vector_type(4)));

#define MFMA16 __builtin_amdgcn_mfma_f32_16x16x32_bf16
#define WAITVM0 asm volatile("s_waitcnt vmcnt(0)" ::: "memory")

__device__ __forceinline__ float fast_exp2(float x) {
#if __has_builtin(__builtin_amdgcn_exp2f)
  return __builtin_amdgcn_exp2f(x);
#else
  return exp2f(x);
#endif
}
__device__ __forceinline__ float fast_log2(float x) {
#if __has_builtin(__builtin_amdgcn_logf)
  return __builtin_amdgcn_logf(x);
#else
  return log2f(x);
#endif
}

__device__ __forceinline__ ushort f2bf(float x) {
  __hip_bfloat16 h = __float2bfloat16(x);
  return __builtin_bit_cast(ushort, h);
}

// byte offset in a 256-byte-row swizzled tile (128 bf16 cols)
__device__ __forceinline__ int swb(int row, int x) {
  return (row << 8) + (x ^ ((row & 15) << 4));
}
// byte offset in a 512-byte-row swizzled tile (256 bf16 cols)
__device__ __forceinline__ int swb9(int row, int x) {
  return (row << 9) + (x ^ ((row & 15) << 4));
}

typedef const __attribute__((address_space(1))) unsigned int g_u32;
typedef __attribute__((address_space(3))) unsigned int l_u32;
__device__ __forceinline__ void gl_lds16(const ushort* g, ushort* l) {
  __builtin_amdgcn_global_load_lds((g_u32*)g, (l_u32*)l, 16, 0, 0);
}

// ---------------- prep: preds1 (bid<32) + posimg convert (bid>=32) ----------
__global__ __launch_bounds__(256) void prep_all(
    const float* __restrict__ f_t, const float* __restrict__ fmap_tp1,
    const float* __restrict__ W1, const float* __restrict__ b1,
    ushort* __restrict__ p1img, ushort* __restrict__ posimg,
    float* __restrict__ out) {
  const int bid = blockIdx.x, t = threadIdx.x;
  if (bid == 0 && t == 0) *out = 0.f;  // replaces memset dispatch
  const int wave = t >> 6, lane = t & 63, lo = lane & 15, hi = lane >> 4;

  if (bid < 32) {
    // ---- preds1: rows rc*32..+32, d-cols dh*64..+64, K=256 ----
    __shared__ __align__(16) ushort sF[32 * 256];  // 16 KB
    __shared__ __align__(16) ushort sW[64 * 256];  // 32 KB
    const int rc = bid >> 1, dh = bid & 1;
#pragma unroll
    for (int k = 0; k < 8; ++k) {
      int idx = t + k * 256;
      int row = idx >> 6, c4 = (idx & 63) << 2;
      float4 v = *(const float4*)(f_t + (size_t)(rc * 32 + row) * 256 + c4);
      ushort4 h = {f2bf(v.x), f2bf(v.y), f2bf(v.z), f2bf(v.w)};
      *(ushort4*)((char*)sF + swb9(row, c4 << 1)) = h;
    }
#pragma unroll
    for (int k = 0; k < 16; ++k) {
      int idx = t + k * 256;
      int row = idx >> 6, c4 = (idx & 63) << 2;
      float4 v = *(const float4*)(W1 + (size_t)(dh * 64 + row) * 256 + c4);
      ushort4 h = {f2bf(v.x), f2bf(v.y), f2bf(v.z), f2bf(v.w)};
      *(ushort4*)((char*)sW + swb9(row, c4 << 1)) = h;
    }
    __syncthreads();
    const int rn = (wave & 1) * 16, wd = (wave >> 1) * 32;
    f32x4 acc[2] = {};
#pragma unroll
    for (int s = 0; s < 8; ++s) {
      int x = s * 64 + hi * 16;
      bf16x8 a = *(const bf16x8*)((const char*)sF + swb9(rn + lo, x));
#pragma unroll
      for (int j = 0; j < 2; ++j) {
        bf16x8 b = *(const bf16x8*)((const char*)sW + swb9(wd + j * 16 + lo, x));
        acc[j] = MFMA16(a, b, acc[j], 0, 0, 0);
      }
    }
#pragma unroll
    for (int j = 0; j < 2; ++j) {
      int d = dh * 64 + wd + j * 16 + lo;
      float bb = b1[d];
#pragma unroll
      for (int e = 0; e < 4; ++e) {
        int R = rc * 32 + rn + hi * 4 + e;
        int tile = R >> 6, rin = R & 63;
        *(ushort*)((char*)p1img + (size_t)tile * 16384 + (rin << 8) +
                   ((2 * d) ^ ((rin & 15) << 4))) =
            f2bf((acc[j][e] + bb) * LOG2E);
      }
    }
  } else {
    // ---- posimg tile (l, mtt): fp32 -> swizzled bf16 ----
    const int bb = bid - 32;
    const int l = bb >> 3, mtt = bb & 7;
    ushort* tile = posimg + (size_t)bb * 8192;
#pragma unroll
    for (int k = 0; k < 8; ++k) {
      int idx = t + k * 256;
      int row = idx >> 5, c4 = (idx & 31) << 2;
      float4 v = *(const float4*)(fmap_tp1 + (size_t)(mtt * 64 + row) * LC + l * 128 + c4);
      ushort4 h = {f2bf(v.x), f2bf(v.y), f2bf(v.z), f2bf(v.w)};
      *(ushort4*)((char*)tile + swb(row, c4 << 1)) = h;
    }
  }
}

// ---------------- fused main ----------------
// Phase A overlays {loc, W2-halves, preds2} into the pos double-buffer.
// Loop = round-4 structure: gl_lds bf16 posimg, 1 barrier/iter.
// __launch_bounds__(512,4): VGPR cap 128 (no spill); 24-wave target was a
// spill trap (r9: VGPR forced to 40, 225 MB scratch writes, 2.5x regression).
__global__ __launch_bounds__(512, 4) void stdim_fused(
    const ushort* __restrict__ p1img, const float* __restrict__ fmap_t,
    const ushort* __restrict__ posimg, const float* __restrict__ W2,
    const float* __restrict__ b2, float* __restrict__ out) {
  __shared__ __align__(16) ushort sB[2][8192];  // 32 KB total
  __shared__ float s_rows[2][64][2];
  __shared__ float s_diag[2][64];
  __shared__ float s_red[8];

  const int bid = blockIdx.x;
  const int work = (bid & 7) * 144 + (bid >> 3);  // XCD-chunked (1152 % 8 == 0)
  const int l = work >> 3, rb = work & 7;
  const int t = threadIdx.x;
  const int wave = t >> 6, lane = t & 63, lo = lane & 15, hi = lane >> 4;
  const int ty_ = wave >> 2, wr = (wave >> 1) & 1, wc = wave & 1;

  // ---- phase A: loc -> sB0, W2 half0 -> sB1 ----
#pragma unroll
  for (int k = 0; k < 4; ++k) {
    int idx = t + k * 512;
    int row = idx >> 5, c4 = (idx & 31) << 2;
    float4 v = *(const float4*)(fmap_t + (size_t)(rb * 64 + row) * LC + l * 128 + c4);
    ushort4 h = {f2bf(v.x), f2bf(v.y), f2bf(v.z), f2bf(v.w)};
    *(ushort4*)((char*)sB[0] + swb(row, c4 << 1)) = h;
  }
#pragma unroll
  for (int k = 0; k < 4; ++k) {
    int idx = t + k * 512;
    int row = idx >> 5, c4 = (idx & 31) << 2;
    float4 v = *(const float4*)(W2 + (size_t)row * 128 + c4);
    ushort4 h = {f2bf(v.x), f2bf(v.y), f2bf(v.z), f2bf(v.w)};
    *(ushort4*)((char*)sB[1] + swb(row, c4 << 1)) = h;
  }
  const int wn = (wave & 1) * 32, wd = (wave >> 1) * 32;  // wd in {0,32,64,96}
  const float b2a = b2[wd + lo], b2b = b2[wd + 16 + lo];
  __syncthreads();

  // ---- preds2 = loc @ W2^T, W2 in two 64-row halves ----
  f32x4 acc2[2][2] = {};
  const int wdl = wd & 63;
  if (wave < 4) {  // wd in {0,32}: half 0
#pragma unroll
    for (int s = 0; s < 4; ++s) {
      int x = s * 64 + hi * 16;
      bf16x8 a0 = *(const bf16x8*)((const char*)sB[0] + swb(wn + lo, x));
      bf16x8 a1 = *(const bf16x8*)((const char*)sB[0] + swb(wn + 16 + lo, x));
#pragma unroll
      for (int j = 0; j < 2; ++j) {
        bf16x8 b = *(const bf16x8*)((const char*)sB[1] + swb(wdl + j * 16 + lo, x));
        acc2[0][j] = MFMA16(a0, b, acc2[0][j], 0, 0, 0);
        acc2[1][j] = MFMA16(a1, b, acc2[1][j], 0, 0, 0);
      }
    }
  }
  __syncthreads();
#pragma unroll
  for (int k = 0; k < 4; ++k) {  // W2 half1 -> sB1
    int idx = t + k * 512;
    int row = idx >> 5, c4 = (idx & 31) << 2;
    float4 v = *(const float4*)(W2 + (size_t)(64 + row) * 128 + c4);
    ushort4 h = {f2bf(v.x), f2bf(v.y), f2bf(v.z), f2bf(v.w)};
    *(ushort4*)((char*)sB[1] + swb(row, c4 << 1)) = h;
  }
  __syncthreads();
  if (wave >= 4) {  // wd in {64,96}: half 1
#pragma unroll
    for (int s = 0; s < 4; ++s) {
      int x = s * 64 + hi * 16;
      bf16x8 a0 = *(const bf16x8*)((const char*)sB[0] + swb(wn + lo, x));
      bf16x8 a1 = *(const bf16x8*)((const char*)sB[0] + swb(wn + 16 + lo, x));
#pragma unroll
      for (int j = 0; j < 2; ++j) {
        bf16x8 b = *(const bf16x8*)((const char*)sB[1] + swb(wdl + j * 16 + lo, x));
        acc2[0][j] = MFMA16(a0, b, acc2[0][j], 0, 0, 0);
        acc2[1][j] = MFMA16(a1, b, acc2[1][j], 0, 0, 0);
      }
    }
  }
  __syncthreads();  // all loc reads done -> sB0 reusable

  // ---- write preds2*log2e -> sB0 ----
#pragma unroll
  for (int i2 = 0; i2 < 2; ++i2)
#pragma unroll
    for (int j = 0; j < 2; ++j)
#pragma unroll
      for (int e = 0; e < 4; ++e) {
        int r = wn + i2 * 16 + hi * 4 + e;
        int d = wd + j * 16 + lo;
        *(ushort*)((char*)sB[0] + (r << 8) + ((2 * d) ^ ((r & 15) << 4))) =
            f2bf((acc2[i2][j][e] + (j ? b2b : b2a)) * LOG2E);
      }
  __syncthreads();  // preds2 visible

  // ---- A fragments to regs (loss1 from p1img global; loss2 from sB0) ----
  bf16x8 af[2][4];
  if (ty_ == 0) {
    const char* aimg = (const char*)(p1img + (size_t)rb * 8192);
#pragma unroll
    for (int rt = 0; rt < 2; ++rt)
#pragma unroll
      for (int s = 0; s < 4; ++s)
        af[rt][s] = *(const bf16x8*)(aimg + swb(wr * 32 + rt * 16 + lo, s * 64 + hi * 16));
  } else {
#pragma unroll
    for (int rt = 0; rt < 2; ++rt)
#pragma unroll
      for (int s = 0; s < 4; ++s)
        af[rt][s] = *(const bf16x8*)((const char*)sB[0] +
                                     swb(wr * 32 + rt * 16 + lo, s * 64 + hi * 16));
  }
  __syncthreads();  // af ds_reads drained -> sB0 reusable for pos tiles

  // ---- stage pos tile 0 via global_load_lds (linear dest == swizzled img) ----
  const ushort* ptile = posimg + (size_t)(l * 8) * 8192;
  const ushort* gsrc = ptile + wave * 1024 + lane * 8;
  {
    ushort* dst = (ushort*)sB[0] + wave * 1024;
    gl_lds16(gsrc, dst);
    gl_lds16(gsrc + 512, dst + 512);
  }
  WAITVM0;
  __syncthreads();

  float sm0[4] = {0.f, 0.f, 0.f, 0.f}, sm1[4] = {0.f, 0.f, 0.f, 0.f};

  // ---- main loop (round-4 structure): prefetch mt+1, 1 barrier/iter ----
#pragma unroll
  for (int mt = 0; mt < 8; ++mt) {
    const int cur = mt & 1;
    if (mt < 7) {
      const ushort* src = gsrc + (size_t)(mt + 1) * 8192;
      ushort* dst = (ushort*)sB[cur ^ 1] + wave * 1024;
      gl_lds16(src, dst);
      gl_lds16(src + 512, dst + 512);
    }
    f32x4 a00 = {}, a01 = {}, a10 = {}, a11 = {};
    __builtin_amdgcn_s_setprio(1);
#pragma unroll
    for (int s = 0; s < 4; ++s) {
      int x = s * 64 + hi * 16;
      bf16x8 b0 = *(const bf16x8*)((const char*)sB[cur] + swb(wc * 32 + lo, x));
      bf16x8 b1 = *(const bf16x8*)((const char*)sB[cur] + swb(wc * 32 + 16 + lo, x));
      a00 = MFMA16(af[0][s], b0, a00, 0, 0, 0);
      a01 = MFMA16(af[0][s], b1, a01, 0, 0, 0);
      a10 = MFMA16(af[1][s], b0, a10, 0, 0, 0);
      a11 = MFMA16(af[1][s], b1, a11, 0, 0, 0);
    }
    __builtin_amdgcn_s_setprio(0);
#pragma unroll
    for (int i = 0; i < 4; ++i) {
      sm0[i] += fast_exp2(a00[i]) + fast_exp2(a01[i]);
      sm1[i] += fast_exp2(a10[i]) + fast_exp2(a11[i]);
    }
    if (mt == rb && wc == wr) {
#pragma unroll
      for (int i = 0; i < 4; ++i) {
        if (lo == hi * 4 + i) {
          s_diag[ty_][wr * 32 + hi * 4 + i] = a00[i];
          s_diag[ty_][wr * 32 + 16 + hi * 4 + i] = a11[i];
        }
      }
    }
    __syncthreads();  // drains vmcnt -> tile mt+1 ready; WAR fence for next prefetch
  }

  // ---- reduce the 16 lo-lanes of each row-group ----
#pragma unroll
  for (int i = 0; i < 4; ++i) {
    float v0 = sm0[i], v1 = sm1[i];
#pragma unroll
    for (int st = 1; st <= 8; st <<= 1) {
      v0 += __shfl_xor(v0, st);
      v1 += __shfl_xor(v1, st);
    }
    sm0[i] = v0;
    sm1[i] = v1;
  }
  if (lo == 0) {
#pragma unroll
    for (int i = 0; i < 4; ++i) {
      s_rows[ty_][wr * 32 + hi * 4 + i][wc] = sm0[i];
      s_rows[ty_][wr * 32 + 16 + hi * 4 + i][wc] = sm1[i];
    }
  }
  __syncthreads();

  float part = 0.f;
  if (t < 128) {
    int ty = t >> 6, r = t & 63;
    float tot = s_rows[ty][r][0] + s_rows[ty][r][1];
    part = fast_log2(tot) - s_diag[ty][r];
  }
#pragma unroll
  for (int st = 1; st <= 32; st <<= 1) part += __shfl_xor(part, st);
  if (lane == 0) s_red[wave] = part;
  __syncthreads();
  if (t == 0) {
    float s = 0.f;
#pragma unroll
    for (int w = 0; w < 8; ++w) s += s_red[w];
    atomicAdd(out, s * (0.6931471805599453f / 73728.0f));
  }
}

extern "C" void kernel_launch(void* const* d_in, const int* in_sizes, int n_in,
                              void* d_out, int out_size, void* d_ws, size_t ws_size,
                              hipStream_t stream) {
  const float* f_t      = (const float*)d_in[0];
  const float* fmap_t   = (const float*)d_in[1];
  const float* fmap_tp1 = (const float*)d_in[2];
  const float* W1       = (const float*)d_in[3];
  const float* b1       = (const float*)d_in[4];
  const float* W2       = (const float*)d_in[5];
  const float* b2       = (const float*)d_in[6];
  float* out = (float*)d_out;

  // ws: p1img 8x8192 ushorts (128 KB) | posimg 1152x8192 ushorts (18.9 MB)
  ushort* p1img  = (ushort*)d_ws;
  ushort* posimg = p1img + 8 * 8192;

  prep_all<<<32 + 1152, 256, 0, stream>>>(f_t, fmap_tp1, W1, b1, p1img, posimg, out);
  stdim_fused<<<1152, 512, 0, stream>>>(p1img, fmap_t, posimg, W2, b2, out);
}

// Round 11
// 163.862 us; speedup vs baseline: 1.3584x; 1.0703x over previous
//
#include <hip/hip_runtime.h>
#include <hip/hip_bf16.h>
#include <math.h>

#define LC 18432              // 144*128
#define LOG2E 1.4426950408889634f

typedef short bf16x8 __attribute__((ext_vector_type(8)));
typedef float f32x4 __attribute__((ext_vector_type(4)));

#define MFMA16 __builtin_amdgcn_mfma_f32_16x16x32_bf16
#define WAITVM0 asm volatile("s_waitcnt vmcnt(0)" ::: "memory")

__device__ __forceinline__ float fast_exp2(float x) {
#if __has_builtin(__builtin_amdgcn_exp2f)
  return __builtin_amdgcn_exp2f(x);
#else
  return exp2f(x);
#endif
}
__device__ __forceinline__ float fast_log2(float x) {
#if __has_builtin(__builtin_amdgcn_logf)
  return __builtin_amdgcn_logf(x);
#else
  return log2f(x);
#endif
}

__device__ __forceinline__ ushort f2bf(float x) {
  __hip_bfloat16 h = __float2bfloat16(x);
  return __builtin_bit_cast(ushort, h);
}

// byte offset in a 256-byte-row swizzled tile (128 bf16 cols)
__device__ __forceinline__ int swb(int row, int x) {
  return (row << 8) + (x ^ ((row & 15) << 4));
}
// byte offset in a 512-byte-row swizzled tile (256 bf16 cols)
__device__ __forceinline__ int swb9(int row, int x) {
  return (row << 9) + (x ^ ((row & 15) << 4));
}

typedef const __attribute__((address_space(1))) unsigned int g_u32;
typedef __attribute__((address_space(3))) unsigned int l_u32;
__device__ __forceinline__ void gl_lds16(const ushort* g, ushort* l) {
  __builtin_amdgcn_global_load_lds((g_u32*)g, (l_u32*)l, 16, 0, 0);
}

// ---------------- prep: preds1 (bid<32) + posimg convert (bid>=32) ----------
__global__ __launch_bounds__(256) void prep_all(
    const float* __restrict__ f_t, const float* __restrict__ fmap_tp1,
    const float* __restrict__ W1, const float* __restrict__ b1,
    ushort* __restrict__ p1img, ushort* __restrict__ posimg,
    float* __restrict__ out) {
  const int bid = blockIdx.x, t = threadIdx.x;
  if (bid == 0 && t == 0) *out = 0.f;  // replaces memset dispatch
  const int wave = t >> 6, lane = t & 63, lo = lane & 15, hi = lane >> 4;

  if (bid < 32) {
    // ---- preds1: rows rc*32..+32, d-cols dh*64..+64, K=256 ----
    __shared__ __align__(16) ushort sF[32 * 256];  // 16 KB
    __shared__ __align__(16) ushort sW[64 * 256];  // 32 KB
    const int rc = bid >> 1, dh = bid & 1;
#pragma unroll
    for (int k = 0; k < 8; ++k) {
      int idx = t + k * 256;
      int row = idx >> 6, c4 = (idx & 63) << 2;
      float4 v = *(const float4*)(f_t + (size_t)(rc * 32 + row) * 256 + c4);
      ushort4 h = {f2bf(v.x), f2bf(v.y), f2bf(v.z), f2bf(v.w)};
      *(ushort4*)((char*)sF + swb9(row, c4 << 1)) = h;
    }
#pragma unroll
    for (int k = 0; k < 16; ++k) {
      int idx = t + k * 256;
      int row = idx >> 6, c4 = (idx & 63) << 2;
      float4 v = *(const float4*)(W1 + (size_t)(dh * 64 + row) * 256 + c4);
      ushort4 h = {f2bf(v.x), f2bf(v.y), f2bf(v.z), f2bf(v.w)};
      *(ushort4*)((char*)sW + swb9(row, c4 << 1)) = h;
    }
    __syncthreads();
    const int rn = (wave & 1) * 16, wd = (wave >> 1) * 32;
    f32x4 acc[2] = {};
#pragma unroll
    for (int s = 0; s < 8; ++s) {
      int x = s * 64 + hi * 16;
      bf16x8 a = *(const bf16x8*)((const char*)sF + swb9(rn + lo, x));
#pragma unroll
      for (int j = 0; j < 2; ++j) {
        bf16x8 b = *(const bf16x8*)((const char*)sW + swb9(wd + j * 16 + lo, x));
        acc[j] = MFMA16(a, b, acc[j], 0, 0, 0);
      }
    }
#pragma unroll
    for (int j = 0; j < 2; ++j) {
      int d = dh * 64 + wd + j * 16 + lo;
      float bb = b1[d];
#pragma unroll
      for (int e = 0; e < 4; ++e) {
        int R = rc * 32 + rn + hi * 4 + e;
        int tile = R >> 6, rin = R & 63;
        *(ushort*)((char*)p1img + (size_t)tile * 16384 + (rin << 8) +
                   ((2 * d) ^ ((rin & 15) << 4))) =
            f2bf((acc[j][e] + bb) * LOG2E);
      }
    }
  } else {
    // ---- posimg tile (l, mtt): fp32 -> swizzled bf16 ----
    const int bb = bid - 32;
    const int l = bb >> 3, mtt = bb & 7;
    ushort* tile = posimg + (size_t)bb * 8192;
#pragma unroll
    for (int k = 0; k < 8; ++k) {
      int idx = t + k * 256;
      int row = idx >> 5, c4 = (idx & 31) << 2;
      float4 v = *(const float4*)(fmap_tp1 + (size_t)(mtt * 64 + row) * LC + l * 128 + c4);
      ushort4 h = {f2bf(v.x), f2bf(v.y), f2bf(v.z), f2bf(v.w)};
      *(ushort4*)((char*)tile + swb(row, c4 << 1)) = h;
    }
  }
}

// ---------------- fused main ----------------
// Phase A overlays {loc, W2-halves, preds2} into the pos double-buffer.
// Loop = round-4 structure: gl_lds bf16 posimg, 1 barrier/iter.
// Plain __launch_bounds__(512): ANY min-waves arg triggers the unified
// VGPR/AGPR split trap (r9: (512,6)->VGPR40/225MB spill; r10: (512,4)->
// VGPR64/103MB spill; r8: plain -> VGPR92, no spill).
__global__ __launch_bounds__(512) void stdim_fused(
    const ushort* __restrict__ p1img, const float* __restrict__ fmap_t,
    const ushort* __restrict__ posimg, const float* __restrict__ W2,
    const float* __restrict__ b2, float* __restrict__ out) {
  __shared__ __align__(16) ushort sB[2][8192];  // 32 KB total
  __shared__ float s_rows[2][64][2];
  __shared__ float s_diag[2][64];
  __shared__ float s_red[8];

  const int bid = blockIdx.x;
  const int work = (bid & 7) * 144 + (bid >> 3);  // XCD-chunked (1152 % 8 == 0)
  const int l = work >> 3, rb = work & 7;
  const int t = threadIdx.x;
  const int wave = t >> 6, lane = t & 63, lo = lane & 15, hi = lane >> 4;
  const int ty_ = wave >> 2, wr = (wave >> 1) & 1, wc = wave & 1;

  // ---- phase A: loc -> sB0, W2 half0 -> sB1 ----
#pragma unroll
  for (int k = 0; k < 4; ++k) {
    int idx = t + k * 512;
    int row = idx >> 5, c4 = (idx & 31) << 2;
    float4 v = *(const float4*)(fmap_t + (size_t)(rb * 64 + row) * LC + l * 128 + c4);
    ushort4 h = {f2bf(v.x), f2bf(v.y), f2bf(v.z), f2bf(v.w)};
    *(ushort4*)((char*)sB[0] + swb(row, c4 << 1)) = h;
  }
#pragma unroll
  for (int k = 0; k < 4; ++k) {
    int idx = t + k * 512;
    int row = idx >> 5, c4 = (idx & 31) << 2;
    float4 v = *(const float4*)(W2 + (size_t)row * 128 + c4);
    ushort4 h = {f2bf(v.x), f2bf(v.y), f2bf(v.z), f2bf(v.w)};
    *(ushort4*)((char*)sB[1] + swb(row, c4 << 1)) = h;
  }
  const int wn = (wave & 1) * 32, wd = (wave >> 1) * 32;  // wd in {0,32,64,96}
  const float b2a = b2[wd + lo], b2b = b2[wd + 16 + lo];
  __syncthreads();

  // ---- preds2 = loc @ W2^T, W2 in two 64-row halves ----
  f32x4 acc2[2][2] = {};
  const int wdl = wd & 63;
  if (wave < 4) {  // wd in {0,32}: half 0
#pragma unroll
    for (int s = 0; s < 4; ++s) {
      int x = s * 64 + hi * 16;
      bf16x8 a0 = *(const bf16x8*)((const char*)sB[0] + swb(wn + lo, x));
      bf16x8 a1 = *(const bf16x8*)((const char*)sB[0] + swb(wn + 16 + lo, x));
#pragma unroll
      for (int j = 0; j < 2; ++j) {
        bf16x8 b = *(const bf16x8*)((const char*)sB[1] + swb(wdl + j * 16 + lo, x));
        acc2[0][j] = MFMA16(a0, b, acc2[0][j], 0, 0, 0);
        acc2[1][j] = MFMA16(a1, b, acc2[1][j], 0, 0, 0);
      }
    }
  }
  __syncthreads();
#pragma unroll
  for (int k = 0; k < 4; ++k) {  // W2 half1 -> sB1
    int idx = t + k * 512;
    int row = idx >> 5, c4 = (idx & 31) << 2;
    float4 v = *(const float4*)(W2 + (size_t)(64 + row) * 128 + c4);
    ushort4 h = {f2bf(v.x), f2bf(v.y), f2bf(v.z), f2bf(v.w)};
    *(ushort4*)((char*)sB[1] + swb(row, c4 << 1)) = h;
  }
  __syncthreads();
  if (wave >= 4) {  // wd in {64,96}: half 1
#pragma unroll
    for (int s = 0; s < 4; ++s) {
      int x = s * 64 + hi * 16;
      bf16x8 a0 = *(const bf16x8*)((const char*)sB[0] + swb(wn + lo, x));
      bf16x8 a1 = *(const bf16x8*)((const char*)sB[0] + swb(wn + 16 + lo, x));
#pragma unroll
      for (int j = 0; j < 2; ++j) {
        bf16x8 b = *(const bf16x8*)((const char*)sB[1] + swb(wdl + j * 16 + lo, x));
        acc2[0][j] = MFMA16(a0, b, acc2[0][j], 0, 0, 0);
        acc2[1][j] = MFMA16(a1, b, acc2[1][j], 0, 0, 0);
      }
    }
  }
  __syncthreads();  // all loc reads done -> sB0 reusable

  // ---- write preds2*log2e -> sB0 ----
#pragma unroll
  for (int i2 = 0; i2 < 2; ++i2)
#pragma unroll
    for (int j = 0; j < 2; ++j)
#pragma unroll
      for (int e = 0; e < 4; ++e) {
        int r = wn + i2 * 16 + hi * 4 + e;
        int d = wd + j * 16 + lo;
        *(ushort*)((char*)sB[0] + (r << 8) + ((2 * d) ^ ((r & 15) << 4))) =
            f2bf((acc2[i2][j][e] + (j ? b2b : b2a)) * LOG2E);
      }
  __syncthreads();  // preds2 visible

  // ---- A fragments to regs (loss1 from p1img global; loss2 from sB0) ----
  bf16x8 af[2][4];
  if (ty_ == 0) {
    const char* aimg = (const char*)(p1img + (size_t)rb * 8192);
#pragma unroll
    for (int rt = 0; rt < 2; ++rt)
#pragma unroll
      for (int s = 0; s < 4; ++s)
        af[rt][s] = *(const bf16x8*)(aimg + swb(wr * 32 + rt * 16 + lo, s * 64 + hi * 16));
  } else {
#pragma unroll
    for (int rt = 0; rt < 2; ++rt)
#pragma unroll
      for (int s = 0; s < 4; ++s)
        af[rt][s] = *(const bf16x8*)((const char*)sB[0] +
                                     swb(wr * 32 + rt * 16 + lo, s * 64 + hi * 16));
  }
  __syncthreads();  // af ds_reads drained -> sB0 reusable for pos tiles

  // ---- stage pos tile 0 via global_load_lds (linear dest == swizzled img) ----
  const ushort* ptile = posimg + (size_t)(l * 8) * 8192;
  const ushort* gsrc = ptile + wave * 1024 + lane * 8;
  {
    ushort* dst = (ushort*)sB[0] + wave * 1024;
    gl_lds16(gsrc, dst);
    gl_lds16(gsrc + 512, dst + 512);
  }
  WAITVM0;
  __syncthreads();

  float sm0[4] = {0.f, 0.f, 0.f, 0.f}, sm1[4] = {0.f, 0.f, 0.f, 0.f};

  // ---- main loop (round-4 structure): prefetch mt+1, 1 barrier/iter ----
#pragma unroll
  for (int mt = 0; mt < 8; ++mt) {
    const int cur = mt & 1;
    if (mt < 7) {
      const ushort* src = gsrc + (size_t)(mt + 1) * 8192;
      ushort* dst = (ushort*)sB[cur ^ 1] + wave * 1024;
      gl_lds16(src, dst);
      gl_lds16(src + 512, dst + 512);
    }
    f32x4 a00 = {}, a01 = {}, a10 = {}, a11 = {};
    __builtin_amdgcn_s_setprio(1);
#pragma unroll
    for (int s = 0; s < 4; ++s) {
      int x = s * 64 + hi * 16;
      bf16x8 b0 = *(const bf16x8*)((const char*)sB[cur] + swb(wc * 32 + lo, x));
      bf16x8 b1 = *(const bf16x8*)((const char*)sB[cur] + swb(wc * 32 + 16 + lo, x));
      a00 = MFMA16(af[0][s], b0, a00, 0, 0, 0);
      a01 = MFMA16(af[0][s], b1, a01, 0, 0, 0);
      a10 = MFMA16(af[1][s], b0, a10, 0, 0, 0);
      a11 = MFMA16(af[1][s], b1, a11, 0, 0, 0);
    }
    __builtin_amdgcn_s_setprio(0);
#pragma unroll
    for (int i = 0; i < 4; ++i) {
      sm0[i] += fast_exp2(a00[i]) + fast_exp2(a01[i]);
      sm1[i] += fast_exp2(a10[i]) + fast_exp2(a11[i]);
    }
    if (mt == rb && wc == wr) {
#pragma unroll
      for (int i = 0; i < 4; ++i) {
        if (lo == hi * 4 + i) {
          s_diag[ty_][wr * 32 + hi * 4 + i] = a00[i];
          s_diag[ty_][wr * 32 + 16 + hi * 4 + i] = a11[i];
        }
      }
    }
    __syncthreads();  // drains vmcnt -> tile mt+1 ready; WAR fence for next prefetch
  }

  // ---- reduce the 16 lo-lanes of each row-group ----
#pragma unroll
  for (int i = 0; i < 4; ++i) {
    float v0 = sm0[i], v1 = sm1[i];
#pragma unroll
    for (int st = 1; st <= 8; st <<= 1) {
      v0 += __shfl_xor(v0, st);
      v1 += __shfl_xor(v1, st);
    }
    sm0[i] = v0;
    sm1[i] = v1;
  }
  if (lo == 0) {
#pragma unroll
    for (int i = 0; i < 4; ++i) {
      s_rows[ty_][wr * 32 + hi * 4 + i][wc] = sm0[i];
      s_rows[ty_][wr * 32 + 16 + hi * 4 + i][wc] = sm1[i];
    }
  }
  __syncthreads();

  float part = 0.f;
  if (t < 128) {
    int ty = t >> 6, r = t & 63;
    float tot = s_rows[ty][r][0] + s_rows[ty][r][1];
    part = fast_log2(tot) - s_diag[ty][r];
  }
#pragma unroll
  for (int st = 1; st <= 32; st <<= 1) part += __shfl_xor(part, st);
  if (lane == 0) s_red[wave] = part;
  __syncthreads();
  if (t == 0) {
    float s = 0.f;
#pragma unroll
    for (int w = 0; w < 8; ++w) s += s_red[w];
    atomicAdd(out, s * (0.6931471805599453f / 73728.0f));
  }
}

extern "C" void kernel_launch(void* const* d_in, const int* in_sizes, int n_in,
                              void* d_out, int out_size, void* d_ws, size_t ws_size,
                              hipStream_t stream) {
  const float* f_t      = (const float*)d_in[0];
  const float* fmap_t   = (const float*)d_in[1];
  const float* fmap_tp1 = (const float*)d_in[2];
  const float* W1       = (const float*)d_in[3];
  const float* b1       = (const float*)d_in[4];
  const float* W2       = (const float*)d_in[5];
  const float* b2       = (const float*)d_in[6];
  float* out = (float*)d_out;

  // ws: p1img 8x8192 ushorts (128 KB) | posimg 1152x8192 ushorts (18.9 MB)
  ushort* p1img  = (ushort*)d_ws;
  ushort* posimg = p1img + 8 * 8192;

  prep_all<<<32 + 1152, 256, 0, stream>>>(f_t, fmap_tp1, W1, b1, p1img, posimg, out);
  stdim_fused<<<1152, 512, 0, stream>>>(p1img, fmap_t, posimg, W2, b2, out);
}